// Round 7
// baseline (177.529 us; speedup 1.0000x reference)
//
#include <hip/hip_runtime.h>

typedef __attribute__((ext_vector_type(8))) short bf16x8;
typedef __attribute__((ext_vector_type(4))) float f32x4;

namespace {

constexpr int B = 32, T = 128, V = 128, F = 64, O = 64;
constexpr int TPB = 8;   // t-tiles per block; grid = (T/TPB, B) = 512 blocks = 2/CU, all resident

// ws layout (bytes):
//   [acat_f bf16: B * (8 ks * 8 r2 * 64 lane) frags * 16B = 2 MiB]   fragment-major Acat
//   [tht_f  bf16: (2 ks * 12 nf * 64 lane) frags * 16B = 24 KiB]     fragment-major ThT
//   [ldg    f32 : B*V = 16 KiB]
constexpr size_t WS_THT_OFF = (size_t)B * 64 * 64 * 8 * 2;   // 2 MiB
constexpr size_t WS_LDG_OFF = WS_THT_OFF + 1536 * 8 * 2;     // +24 KiB

__device__ inline unsigned short f2bf(float f) {
    unsigned u = __builtin_bit_cast(unsigned, f);
    u += 0x7FFFu + ((u >> 16) & 1u);
    return (unsigned short)(u >> 16);
}

__device__ inline bf16x8 pack8(const float4 a, const float4 b) {
    uint4 u;
    u.x = f2bf(a.x) | ((unsigned)f2bf(a.y) << 16);
    u.y = f2bf(a.z) | ((unsigned)f2bf(a.w) << 16);
    u.z = f2bf(b.x) | ((unsigned)f2bf(b.y) << 16);
    u.w = f2bf(b.z) | ((unsigned)f2bf(b.w) << 16);
    return __builtin_bit_cast(bf16x8, u);
}

// ---------------- prep: fragment-major Acat/ThT, ldiag (unchanged from r6) ----------------
__global__ __launch_bounds__(256) void prep(const float* __restrict__ W,
                                            const float* __restrict__ Theta,
                                            unsigned short* __restrict__ acat_f,
                                            unsigned short* __restrict__ tht_f,
                                            float* __restrict__ ldg) {
    const int tid = threadIdx.x;
    if (blockIdx.x == B) {
        for (int i = 0; i < 6; ++i) {
            int fi = tid + i * 256;                 // [0,1536)
            int ks = fi / 768, rem = fi % 768;
            int nf = rem >> 6, lane = rem & 63;
            int n = nf * 16 + (lane & 15);
            int f0 = ks * 32 + (lane >> 4) * 8;
            unsigned short vals[8];
#pragma unroll
            for (int j = 0; j < 8; ++j) {
                int f = f0 + j;
                float v;
                if (n < 64)       v = Theta[f * 64 + n] - Theta[2 * 4096 + f * 64 + n];
                else if (n < 128) v = Theta[4096 + f * 64 + (n - 64)];
                else              v = Theta[2 * 4096 + f * 64 + (n - 128)];
                vals[j] = f2bf(v);
            }
            *(bf16x8*)(tht_f + (size_t)fi * 8) = *(bf16x8*)vals;
        }
        return;
    }
    const int b = blockIdx.x;
    const float* Wb = W + (size_t)b * V * V;
    __shared__ float Wl[V][V + 1];
    for (int i = 0; i < V * V / 256; ++i) {
        int idx = tid + i * 256;
        Wl[idx >> 7][idx & 127] = Wb[idx];
    }
    __syncthreads();
    if (tid < V) {
        float s = 0.f;
        for (int i = 0; i < V; ++i) s += Wl[i][tid];       // deg[u] = sum_i W[i][u]
        ldg[b * V + tid] = s - 1.0f - Wl[tid][tid];        // ldiag
    }
    unsigned short* ab_f = acat_f + (size_t)b * 32768;
    for (int i = 0; i < 16; ++i) {
        int fi = tid + i * 256;                    // [0,4096)
        int ks = fi >> 9, rem = fi & 511;
        int r2 = rem >> 6, lane = rem & 63;
        int u = r2 * 16 + (lane & 15);
        int kv0 = ks * 32 + (lane >> 4) * 8;
        unsigned short vals[8];
#pragma unroll
        for (int j = 0; j < 8; ++j) {
            int kv = kv0 + j, v = kv & 127;
            float wv = Wl[v][u];
            float val = (v == u) ? 0.f : ((kv < 128) ? -wv : 2.f * wv * wv);
            vals[j] = f2bf(val);
        }
        *(bf16x8*)(ab_f + (size_t)fi * 8) = *(bf16x8*)vals;
    }
}

// ---------------- main: t-batched, double-buffered global_load_lds pipeline ----------------
__global__ __launch_bounds__(256, 2) void graph_conv_main(
    const float* __restrict__ x, const unsigned short* __restrict__ acat_f,
    const unsigned short* __restrict__ tht_f, const float* __restrict__ ldg,
    float* __restrict__ out) {
    const int t0 = blockIdx.x * TPB, b = blockIdx.y;
    const int tid = threadIdx.x;
    const int lane = tid & 63, w = tid >> 6;
    const int lr = lane & 15, lg = lane >> 4;

    __shared__ __align__(16) float xbuf[2][V * F];        // 2 x 32 KB fp32 (gl_lds targets, linear)
    __shared__ __align__(16) unsigned short zc1[4096];    // 8 KB  Z1 (o-major, swizzled)
    __shared__ __align__(16) unsigned short zc2[4096];    // 8 KB  Z2
    // total 80 KB -> 2 blocks/CU

    const float* xb = x + ((size_t)(b * T + t0)) * (V * F);
    const float* ldb = ldg + b * V;

    // LDS chunk n (16B, linear) holds x[row][c*4 .. +4) with row = n>>4, c = (n&15) ^ (row&7):
    // inverse swizzle carried by the GLOBAL address (rule #21); LDS dest stays linear.
    // wave w stages its own 8 KB quarter (rows 32w..32w+31) = 8 gl_lds insts.
    auto stage = [&](int tt, int buf) {
        const float* src = xb + (size_t)tt * (V * F);
        char* lbase = (char*)&xbuf[buf][0] + w * 8192;
#pragma unroll
        for (int j = 0; j < 8; ++j) {
            int n = w * 512 + j * 64 + lane;
            int row = n >> 4;
            int c = (n & 15) ^ (row & 7);
            const float* g = src + row * 64 + c * 4;
            __builtin_amdgcn_global_load_lds(
                (const __attribute__((address_space(1))) void*)g,
                (__attribute__((address_space(3))) void*)(lbase + j * 1024), 16, 0, 0);
        }
    };

    stage(0, 0);
    __syncthreads();   // drain: xbuf[0] ready
    int cur = 0;

    for (int tt = 0; tt < TPB; ++tt) {
        // ---- issue prefetch of x(tt+1); drained at barrier B1 (hides under Z-phase) ----
        if (tt + 1 < TPB) stage(tt + 1, cur ^ 1);

        // ---- xa fragments: fp32 from swizzled LDS, cvt to bf16 ----
        const char* xc = (const char*)&xbuf[cur][0];
        bf16x8 xa[2][2];
#pragma unroll
        for (int vf = 0; vf < 2; ++vf) {
            const int row = w * 32 + vf * 16 + lr;
            const int rb = row * 256, rs = row & 7;
#pragma unroll
            for (int ks = 0; ks < 2; ++ks) {
                const int c0 = ks * 8 + lg * 2;
                float4 a = *(const float4*)(xc + rb + ((c0 ^ rs) << 4));
                float4 bq = *(const float4*)(xc + rb + (((c0 + 1) ^ rs) << 4));
                xa[vf][ks] = pack8(a, bq);
            }
        }

        f32x4 acc[2][4], z[2][4];
#pragma unroll
        for (int vf = 0; vf < 2; ++vf)
#pragma unroll
            for (int of = 0; of < 4; ++of) {
                acc[vf][of] = (f32x4){0.f, 0.f, 0.f, 0.f};
                z[vf][of] = (f32x4){0.f, 0.f, 0.f, 0.f};
            }

        // ---- part 1: Zm -> acc, Z1 -> z (tb coalesced from fragment-major global, L2-hot) ----
#pragma unroll
        for (int ks = 0; ks < 2; ++ks)
#pragma unroll
            for (int nf = 0; nf < 8; ++nf) {
                bf16x8 tb = *(const bf16x8*)(tht_f + ((size_t)(ks * 12 + nf) * 64 + lane) * 8);
                if (nf < 4) {
                    acc[0][nf] = __builtin_amdgcn_mfma_f32_16x16x32_bf16(xa[0][ks], tb, acc[0][nf], 0, 0, 0);
                    acc[1][nf] = __builtin_amdgcn_mfma_f32_16x16x32_bf16(xa[1][ks], tb, acc[1][nf], 0, 0, 0);
                } else {
                    z[0][nf - 4] = __builtin_amdgcn_mfma_f32_16x16x32_bf16(xa[0][ks], tb, z[0][nf - 4], 0, 0, 0);
                    z[1][nf - 4] = __builtin_amdgcn_mfma_f32_16x16x32_bf16(xa[1][ks], tb, z[1][nf - 4], 0, 0, 0);
                }
            }

        // ---- diag(Z1) + write Z1 -> zc1; reuse z regs for Z2 ----
        f32x4 ldv[2];
#pragma unroll
        for (int vf = 0; vf < 2; ++vf) {
            ldv[vf] = *(const f32x4*)(ldb + w * 32 + 16 * vf + lg * 4);
#pragma unroll
            for (int of = 0; of < 4; ++of) acc[vf][of] += ldv[vf] * z[vf][of];
        }
#pragma unroll
        for (int vf = 0; vf < 2; ++vf) {
            const int vcol = w * 32 + 16 * vf + lg * 4;
#pragma unroll
            for (int of = 0; of < 4; ++of) {
                const int rowz = of * 16 + lr;
                f32x4 zv = z[vf][of];
                uint2 q;
                q.x = f2bf(zv[0]) | ((unsigned)f2bf(zv[1]) << 16);
                q.y = f2bf(zv[2]) | ((unsigned)f2bf(zv[3]) << 16);
                *(uint2*)((char*)zc1 + rowz * 256 + ((vcol * 2) ^ ((rowz & 7) << 4))) = q;
                z[vf][of] = (f32x4){0.f, 0.f, 0.f, 0.f};
            }
        }

        // ---- part 2: Z2 into reused z regs ----
#pragma unroll
        for (int ks = 0; ks < 2; ++ks)
#pragma unroll
            for (int nf = 0; nf < 4; ++nf) {
                bf16x8 tb = *(const bf16x8*)(tht_f + ((size_t)(ks * 12 + 8 + nf) * 64 + lane) * 8);
                z[0][nf] = __builtin_amdgcn_mfma_f32_16x16x32_bf16(xa[0][ks], tb, z[0][nf], 0, 0, 0);
                z[1][nf] = __builtin_amdgcn_mfma_f32_16x16x32_bf16(xa[1][ks], tb, z[1][nf], 0, 0, 0);
            }

        // ---- diag(Z2) + write Z2 -> zc2 ----
#pragma unroll
        for (int vf = 0; vf < 2; ++vf) {
            f32x4 ld2 = 2.0f * ldv[vf] * ldv[vf];
#pragma unroll
            for (int of = 0; of < 4; ++of) acc[vf][of] += ld2 * z[vf][of];
        }
#pragma unroll
        for (int vf = 0; vf < 2; ++vf) {
            const int vcol = w * 32 + 16 * vf + lg * 4;
#pragma unroll
            for (int of = 0; of < 4; ++of) {
                const int rowz = of * 16 + lr;
                f32x4 zv = z[vf][of];
                uint2 q;
                q.x = f2bf(zv[0]) | ((unsigned)f2bf(zv[1]) << 16);
                q.y = f2bf(zv[2]) | ((unsigned)f2bf(zv[3]) << 16);
                *(uint2*)((char*)zc2 + rowz * 256 + ((vcol * 2) ^ ((rowz & 7) << 4))) = q;
            }
        }

        __syncthreads();   // B1: z visible; compiler's vmcnt(0) drain completes prefetch of xbuf[cur^1]

        // ---- contraction: acc += Acat[u,0:256] @ [Z1;Z2] ----
#pragma unroll
        for (int ks = 0; ks < 8; ++ks) {
            bf16x8 af[2];
#pragma unroll
            for (int uf = 0; uf < 2; ++uf)
                af[uf] = *(const bf16x8*)(acat_f +
                         (((size_t)b * 64 + ks * 8 + (w * 2 + uf)) * 64 + lane) * 8);
            const char* zsrc = (ks < 4) ? (const char*)zc1 : (const char*)zc2;
            const int kcol = (ks & 3) * 64 + lg * 16;
#pragma unroll
            for (int of = 0; of < 4; ++of) {
                const int rowz = of * 16 + lr;
                bf16x8 zb = *(const bf16x8*)(zsrc + rowz * 256 + (kcol ^ ((rowz & 7) << 4)));
                acc[0][of] = __builtin_amdgcn_mfma_f32_16x16x32_bf16(af[0], zb, acc[0][of], 0, 0, 0);
                acc[1][of] = __builtin_amdgcn_mfma_f32_16x16x32_bf16(af[1], zb, acc[1][of], 0, 0, 0);
            }
        }

        // ---- epilogue: relu + store t = t0+tt ----
        float* obt = out + ((size_t)(b * T + t0 + tt)) * (V * O);
#pragma unroll
        for (int vf = 0; vf < 2; ++vf)
#pragma unroll
            for (int of = 0; of < 4; ++of)
#pragma unroll
                for (int j = 0; j < 4; ++j) {
                    const int u = w * 32 + 16 * vf + lg * 4 + j;
                    const int o = of * 16 + lr;
                    const float r = acc[vf][of][j];
                    obt[u * 64 + o] = r > 0.f ? r : 0.f;
                }

        __syncthreads();   // B2: zc1/zc2 reads done before next iter overwrites them
        cur ^= 1;
    }
}

}  // namespace

extern "C" void kernel_launch(void* const* d_in, const int* in_sizes, int n_in,
                              void* d_out, int out_size, void* d_ws, size_t ws_size,
                              hipStream_t stream) {
    const float* x = (const float*)d_in[0];      // (B,T,V,F)
    const float* W = (const float*)d_in[1];      // (B,V,V)
    const float* Theta = (const float*)d_in[2];  // (3,F,O)
    float* outp = (float*)d_out;                 // (B,T,V,O)

    unsigned short* acat_f = (unsigned short*)d_ws;
    unsigned short* tht_f = (unsigned short*)((char*)d_ws + WS_THT_OFF);
    float* ldg = (float*)((char*)d_ws + WS_LDG_OFF);

    prep<<<B + 1, 256, 0, stream>>>(W, Theta, acat_f, tht_f, ldg);
    graph_conv_main<<<dim3(T / TPB, B), 256, 0, stream>>>(x, acat_f, tht_f, ldg, outp);
}

// Round 8
// 77.517 us; speedup vs baseline: 2.2902x; 2.2902x over previous
//
#include <hip/hip_runtime.h>

typedef __attribute__((ext_vector_type(8))) short bf16x8;
typedef __attribute__((ext_vector_type(4))) float f32x4;

namespace {

constexpr int B = 32, T = 128, V = 128, F = 64, O = 64;
constexpr int TPB = 16;   // t-tiles per block; grid = (T/TPB=8, B=32) = 256 blocks = 1/CU

// ws layout (bytes):
//   [acat_f bf16: B * (8 ks * 8 r2 * 64 lane) frags * 16B = 2 MiB]   fragment-major Acat
//   [tht_f  bf16: (2 ks * 12 nf * 64 lane) frags * 16B = 24 KiB]     fragment-major ThT
//   [ldg    f32 : B*V = 16 KiB]
constexpr size_t WS_THT_OFF = (size_t)B * 64 * 64 * 8 * 2;   // 2 MiB
constexpr size_t WS_LDG_OFF = WS_THT_OFF + 1536 * 8 * 2;     // +24 KiB

__device__ inline unsigned short f2bf(float f) {
    unsigned u = __builtin_bit_cast(unsigned, f);
    u += 0x7FFFu + ((u >> 16) & 1u);
    return (unsigned short)(u >> 16);
}

// ---------------- prep: fragment-major Acat/ThT, ldiag (unchanged from r6) ----------------
__global__ __launch_bounds__(256) void prep(const float* __restrict__ W,
                                            const float* __restrict__ Theta,
                                            unsigned short* __restrict__ acat_f,
                                            unsigned short* __restrict__ tht_f,
                                            float* __restrict__ ldg) {
    const int tid = threadIdx.x;
    if (blockIdx.x == B) {
        // tht_f frag fi = ks*12+nf (nf 0..11); lane holds ThT[n=nf*16+lr][f=ks*32+lg*8 ..+8)
        for (int i = 0; i < 6; ++i) {
            int fi = tid + i * 256;                 // [0,1536)
            int ks = fi / 768, rem = fi % 768;
            int nf = rem >> 6, lane = rem & 63;
            int n = nf * 16 + (lane & 15);
            int f0 = ks * 32 + (lane >> 4) * 8;
            unsigned short vals[8];
#pragma unroll
            for (int j = 0; j < 8; ++j) {
                int f = f0 + j;
                float v;
                if (n < 64)       v = Theta[f * 64 + n] - Theta[2 * 4096 + f * 64 + n];
                else if (n < 128) v = Theta[4096 + f * 64 + (n - 64)];
                else              v = Theta[2 * 4096 + f * 64 + (n - 128)];
                vals[j] = f2bf(v);
            }
            *(bf16x8*)(tht_f + (size_t)fi * 8) = *(bf16x8*)vals;
        }
        return;
    }
    const int b = blockIdx.x;
    const float* Wb = W + (size_t)b * V * V;
    __shared__ float Wl[V][V + 1];
    for (int i = 0; i < V * V / 256; ++i) {
        int idx = tid + i * 256;
        Wl[idx >> 7][idx & 127] = Wb[idx];
    }
    __syncthreads();
    if (tid < V) {
        float s = 0.f;
        for (int i = 0; i < V; ++i) s += Wl[i][tid];       // deg[u] = sum_i W[i][u]
        ldg[b * V + tid] = s - 1.0f - Wl[tid][tid];        // ldiag
    }
    // acat_f frag fi = ks*8 + r2 (r2 = u/16); lane holds Acat[u=r2*16+lr][kv=ks*32+lg*8 ..+8)
    unsigned short* ab_f = acat_f + (size_t)b * 32768;
    for (int i = 0; i < 16; ++i) {
        int fi = tid + i * 256;                    // [0,4096)
        int ks = fi >> 9, rem = fi & 511;
        int r2 = rem >> 6, lane = rem & 63;
        int u = r2 * 16 + (lane & 15);
        int kv0 = ks * 32 + (lane >> 4) * 8;
        unsigned short vals[8];
#pragma unroll
        for (int j = 0; j < 8; ++j) {
            int kv = kv0 + j, v = kv & 127;
            float wv = Wl[v][u];
            float val = (v == u) ? 0.f : ((kv < 128) ? -wv : 2.f * wv * wv);
            vals[j] = f2bf(val);
        }
        *(bf16x8*)(ab_f + (size_t)fi * 8) = *(bf16x8*)vals;
    }
}

// ---------------- main: 512-thread block per (b, 16 t's); ALL loop operands in LDS ----------------
__global__ __launch_bounds__(512, 2) void graph_conv_main(
    const float* __restrict__ x, const unsigned short* __restrict__ acat_f,
    const unsigned short* __restrict__ tht_f, const float* __restrict__ ldg,
    float* __restrict__ out) {
    const int t0 = blockIdx.x * TPB, b = blockIdx.y;
    const int tid = threadIdx.x;                 // 0..511
    const int lane = tid & 63, w = tid >> 6;     // 8 waves; wave w owns rows [16w, 16w+16)
    const int lr = lane & 15, lg = lane >> 4;

    __shared__ __align__(16) unsigned short acat_s[32768];   // 64 KB, staged once
    __shared__ __align__(16) unsigned short tht_s[12288];    // 24 KB, staged once
    __shared__ __align__(16) unsigned short xbuf[2][8192];   // 2 x 16 KB bf16 x-tiles
    __shared__ __align__(16) unsigned short zc1[4096];       // 8 KB Z1^T
    __shared__ __align__(16) unsigned short zc2[4096];       // 8 KB Z2^T
    // total 136 KB -> 1 block/CU (8 waves)

    const float* xb = x + ((size_t)(b * T + t0)) * (V * F);

    // ---- stage acat_s / tht_s via global_load_lds (byte copies, fragment-major) ----
    {
        const unsigned short* ag = acat_f + (size_t)b * 32768;
#pragma unroll
        for (int i = 0; i < 8; ++i) {
            int c = tid + i * 512;               // 4096 chunks of 16B
            __builtin_amdgcn_global_load_lds(
                (const __attribute__((address_space(1))) void*)(ag + c * 8),
                (__attribute__((address_space(3))) void*)(acat_s + c * 8), 16, 0, 0);
        }
#pragma unroll
        for (int i = 0; i < 3; ++i) {
            int c = tid + i * 512;               // 1536 chunks
            __builtin_amdgcn_global_load_lds(
                (const __attribute__((address_space(1))) void*)(tht_f + c * 8),
                (__attribute__((address_space(3))) void*)(tht_s + c * 8), 16, 0, 0);
        }
    }

    // ---- ldiag fragment, hoisted (constant across t) ----
    const float* ldb = ldg + b * V;
    const f32x4 ldv = *(const f32x4*)(ldb + 16 * w + lg * 4);
    const f32x4 ld2v = 2.0f * ldv * ldv;

    // per-thread x chunk: 4 float4 (16 floats); cvt+swizzled write into xbuf[buf]
    float4 pf[4];
    auto load_pf = [&](int tt) {
        const float4* src = (const float4*)(xb + (size_t)tt * (V * F));
#pragma unroll
        for (int i = 0; i < 4; ++i) pf[i] = src[tid + i * 512];
    };
    auto store_pf = [&](int buf) {
#pragma unroll
        for (int i = 0; i < 4; ++i) {
            int p = tid + i * 512;               // float4 idx in 128x64 tile
            int row = p >> 4, c4 = p & 15;
            uint2 q;
            q.x = f2bf(pf[i].x) | ((unsigned)f2bf(pf[i].y) << 16);
            q.y = f2bf(pf[i].z) | ((unsigned)f2bf(pf[i].w) << 16);
            *(uint2*)((char*)xbuf[buf] + row * 128 + ((c4 * 8) ^ ((row & 7) << 4))) = q;
        }
    };

    load_pf(0);
    store_pf(0);       // compiler waits pf here (also drains acat/tht gl_lds)
    __syncthreads();   // staging + xbuf[0] ready
    int cur = 0;

    for (int tt = 0; tt < TPB; ++tt) {
        // ---- issue x(tt+1) prefetch into regs; nothing consumes vmcnt until store_pf ----
        if (tt + 1 < TPB) load_pf(tt + 1);

        // ---- xa fragments from xbuf[cur] (own 16-row slab) ----
        bf16x8 xa[2];
        {
            const int row = 16 * w + lr;
            const int rb = row * 128, rs = (row & 7) << 4;
#pragma unroll
            for (int ks = 0; ks < 2; ++ks)
                xa[ks] = *(const bf16x8*)((const char*)xbuf[cur] + rb + ((ks * 64 + lg * 16) ^ rs));
        }

        f32x4 acc[4], z[4];
#pragma unroll
        for (int of = 0; of < 4; ++of) {
            acc[of] = (f32x4){0.f, 0.f, 0.f, 0.f};
            z[of] = (f32x4){0.f, 0.f, 0.f, 0.f};
        }

        // ---- part 1: Zm -> acc (nf 0..3), Z1 -> z (nf 4..7); tb from LDS ----
#pragma unroll
        for (int ks = 0; ks < 2; ++ks)
#pragma unroll
            for (int nf = 0; nf < 8; ++nf) {
                bf16x8 tb = *(const bf16x8*)(tht_s + ((ks * 12 + nf) * 64 + lane) * 8);
                if (nf < 4) acc[nf] = __builtin_amdgcn_mfma_f32_16x16x32_bf16(xa[ks], tb, acc[nf], 0, 0, 0);
                else        z[nf - 4] = __builtin_amdgcn_mfma_f32_16x16x32_bf16(xa[ks], tb, z[nf - 4], 0, 0, 0);
            }

        // ---- diag(Z1) + write Z1^T -> zc1; reuse z regs ----
        {
            const int vcol = 16 * w + lg * 4;
#pragma unroll
            for (int of = 0; of < 4; ++of) {
                acc[of] += ldv * z[of];
                const int rowz = of * 16 + lr;
                f32x4 zv = z[of];
                uint2 q;
                q.x = f2bf(zv[0]) | ((unsigned)f2bf(zv[1]) << 16);
                q.y = f2bf(zv[2]) | ((unsigned)f2bf(zv[3]) << 16);
                *(uint2*)((char*)zc1 + rowz * 256 + ((vcol * 2) ^ ((rowz & 7) << 4))) = q;
                z[of] = (f32x4){0.f, 0.f, 0.f, 0.f};
            }
        }

        // ---- part 2: Z2 (nf 8..11) ----
#pragma unroll
        for (int ks = 0; ks < 2; ++ks)
#pragma unroll
            for (int nf = 0; nf < 4; ++nf) {
                bf16x8 tb = *(const bf16x8*)(tht_s + ((ks * 12 + 8 + nf) * 64 + lane) * 8);
                z[nf] = __builtin_amdgcn_mfma_f32_16x16x32_bf16(xa[ks], tb, z[nf], 0, 0, 0);
            }

        // ---- diag(Z2) + write Z2^T -> zc2 ----
        {
            const int vcol = 16 * w + lg * 4;
#pragma unroll
            for (int of = 0; of < 4; ++of) {
                acc[of] += ld2v * z[of];
                const int rowz = of * 16 + lr;
                f32x4 zv = z[of];
                uint2 q;
                q.x = f2bf(zv[0]) | ((unsigned)f2bf(zv[1]) << 16);
                q.y = f2bf(zv[2]) | ((unsigned)f2bf(zv[3]) << 16);
                *(uint2*)((char*)zc2 + rowz * 256 + ((vcol * 2) ^ ((rowz & 7) << 4))) = q;
            }
        }

        __syncthreads();   // B: zc1/zc2 visible (pf loads are long done; drain is free)

        // ---- contraction: acc += Acat[u,0:256] @ [Z1;Z2]; af from LDS ----
#pragma unroll
        for (int ks = 0; ks < 8; ++ks) {
            bf16x8 af = *(const bf16x8*)(acat_s + ((ks * 8 + w) * 64 + lane) * 8);
            const char* zsrc = (ks < 4) ? (const char*)zc1 : (const char*)zc2;
            const int kcol = (ks & 3) * 64 + lg * 16;
#pragma unroll
            for (int of = 0; of < 4; ++of) {
                const int rowz = of * 16 + lr;
                bf16x8 zb = *(const bf16x8*)(zsrc + rowz * 256 + (kcol ^ ((rowz & 7) << 4)));
                acc[of] = __builtin_amdgcn_mfma_f32_16x16x32_bf16(af, zb, acc[of], 0, 0, 0);
            }
        }

        // ---- write x(tt+1) into xbuf[cur^1] (pf consumed here, post-compute) ----
        if (tt + 1 < TPB) store_pf(cur ^ 1);

        // ---- epilogue: relu + store t = t0+tt ----
        float* obt = out + ((size_t)(b * T + t0 + tt)) * (V * O);
#pragma unroll
        for (int of = 0; of < 4; ++of)
#pragma unroll
            for (int j = 0; j < 4; ++j) {
                const int u = 16 * w + lg * 4 + j;
                const int o = of * 16 + lr;
                const float r = acc[of][j];
                obt[u * 64 + o] = r > 0.f ? r : 0.f;
            }

        __syncthreads();   // C: zc reads done; xbuf[cur^1] ready for next iter
        cur ^= 1;
    }
}

}  // namespace

extern "C" void kernel_launch(void* const* d_in, const int* in_sizes, int n_in,
                              void* d_out, int out_size, void* d_ws, size_t ws_size,
                              hipStream_t stream) {
    const float* x = (const float*)d_in[0];      // (B,T,V,F)
    const float* W = (const float*)d_in[1];      // (B,V,V)
    const float* Theta = (const float*)d_in[2];  // (3,F,O)
    float* outp = (float*)d_out;                 // (B,T,V,O)

    unsigned short* acat_f = (unsigned short*)d_ws;
    unsigned short* tht_f = (unsigned short*)((char*)d_ws + WS_THT_OFF);
    float* ldg = (float*)((char*)d_ws + WS_LDG_OFF);

    prep<<<B + 1, 256, 0, stream>>>(W, Theta, acat_f, tht_f, ldg);
    graph_conv_main<<<dim3(T / TPB, B), 512, 0, stream>>>(x, acat_f, tht_f, ldg, outp);
}